// Round 3
// baseline (313.935 us; speedup 1.0000x reference)
//
#include <hip/hip_runtime.h>

typedef unsigned short u16;
typedef __attribute__((ext_vector_type(8))) short short8;
typedef __attribute__((ext_vector_type(4))) float f32x4;

#define CB 2
#define CS 2048
#define CD 1024
#define CH 16
#define CDH 64
#define CDFF 4096
#define NQB (CS / 64)   // 32 q-blocks of 64

__device__ __forceinline__ u16 f2bf(float f){
  union { float f; unsigned u; } x; x.f = f;
  unsigned r = (x.u + 0x7fffu + ((x.u >> 16) & 1u)) >> 16;
  return (u16)r;
}

// cheap round for positive values (P matrix): round-half-up, 2 VALU ops
__device__ __forceinline__ u16 f2bf_pos(float f){
  union { float f; unsigned u; } x; x.f = f;
  return (u16)((x.u + 0x8000u) >> 16);
}

__device__ __forceinline__ void gload_lds16(const void* g, void* l){
  __builtin_amdgcn_global_load_lds(
    (const __attribute__((address_space(1))) void*)(unsigned long long)g,
    (__attribute__((address_space(3))) void*)(unsigned long long)l,
    16, 0, 0);
}

// LDS XOR swizzle: LDS 8-elem block j of row r holds global block j^(r&7).
// Staging loads global col block (lane&7)^srow; fragment reads XOR with lr&7.
// Kills the 16-way bank conflict of the row-stride-128B layout.

// ---------------- fused prep: all 6 weight transposes + LN1, one launch
struct TPAll { const float* s[6]; u16* d[6]; };

__global__ __launch_bounds__(256)
void prep_all(TPAll p, const float* __restrict__ x, const float* __restrict__ g1,
              const float* __restrict__ be1, u16* __restrict__ yln)
{
  const int g = blockIdx.x >> 12;
  const int id = blockIdx.x & 4095;
  const int tid = threadIdx.x;

  if (g == 3){
    // ---- LN1 row
    const int row = id;
    const int lane = tid & 63, wave = tid >> 6;
    const float4 v = ((const float4*)(x + (size_t)row * CD))[tid];
    float s  = v.x + v.y + v.z + v.w;
    float s2 = v.x*v.x + v.y*v.y + v.z*v.z + v.w*v.w;
    #pragma unroll
    for (int m = 1; m < 64; m <<= 1){ s += __shfl_xor(s, m); s2 += __shfl_xor(s2, m); }
    __shared__ float red[8];
    if (lane == 0){ red[wave] = s; red[4 + wave] = s2; }
    __syncthreads();
    s  = red[0] + red[1] + red[2] + red[3];
    s2 = red[4] + red[5] + red[6] + red[7];
    const float mu = s * (1.0f / CD);
    const float var = s2 * (1.0f / CD) - mu * mu;
    const float rs = rsqrtf(var + 1e-5f);
    const float4 gv = ((const float4*)g1)[tid];
    const float4 bv = ((const float4*)be1)[tid];
    ushort4 o;
    o.x = f2bf((v.x - mu) * rs * gv.x + bv.x);
    o.y = f2bf((v.y - mu) * rs * gv.y + bv.y);
    o.z = f2bf((v.z - mu) * rs * gv.z + bv.z);
    o.w = f2bf((v.w - mu) * rs * gv.w + bv.w);
    ((ushort4*)yln)[(size_t)row * (CD / 4) + tid] = o;
    return;
  }

  // ---- transpose tile
  __shared__ float t[32][33];
  const float* __restrict__ in;
  u16* __restrict__ out;
  int K, N, n0, k0;
  if (g == 0){
    const int w = id >> 10, tile = id & 1023;
    in = p.s[w]; out = p.d[w]; K = 1024; N = 1024;
    n0 = (tile & 31) * 32; k0 = (tile >> 5) * 32;
  } else if (g == 1){
    in = p.s[4]; out = p.d[4]; K = 1024; N = 4096;
    n0 = (id & 127) * 32; k0 = (id >> 7) * 32;
  } else {
    in = p.s[5]; out = p.d[5]; K = 4096; N = 1024;
    n0 = (id & 31) * 32; k0 = (id >> 5) * 32;
  }
  const int c = tid & 31, r4 = tid >> 5;
  #pragma unroll
  for (int i = 0; i < 4; i++){
    int r = r4 + i * 8;
    t[r][c] = in[(size_t)(k0 + r) * N + n0 + c];
  }
  __syncthreads();
  #pragma unroll
  for (int i = 0; i < 4; i++){
    int r = r4 + i * 8;
    out[(size_t)(n0 + r) * K + k0 + c] = f2bf(t[c][r]);
  }
}

// ---------------- LayerNorm: fp32 row [1024] -> bf16 row, one block per row
// MODE 0: LN only.  MODE 2: also write aux = v + bias (fp32, may alias xin)
template<int MODE>
__global__ __launch_bounds__(256)
void ln_bf16(const float* __restrict__ xin, const float* __restrict__ g,
             const float* __restrict__ be, u16* __restrict__ outp,
             float4* __restrict__ aux, const float* __restrict__ bias)
{
  const int row = blockIdx.x, tid = threadIdx.x;
  const int lane = tid & 63, wave = tid >> 6;
  const float4 v = ((const float4*)(xin + (size_t)row * CD))[tid];
  float s  = v.x + v.y + v.z + v.w;
  float s2 = v.x*v.x + v.y*v.y + v.z*v.z + v.w*v.w;
  #pragma unroll
  for (int m = 1; m < 64; m <<= 1){ s += __shfl_xor(s, m); s2 += __shfl_xor(s2, m); }
  __shared__ float red[8];
  if (lane == 0){ red[wave] = s; red[4 + wave] = s2; }

  if (MODE == 2){
    const float4 b4 = ((const float4*)bias)[tid];
    float4 w = v;
    w.x += b4.x; w.y += b4.y; w.z += b4.z; w.w += b4.w;
    aux[(size_t)row * 256 + tid] = w;
  }

  __syncthreads();
  s  = red[0] + red[1] + red[2] + red[3];
  s2 = red[4] + red[5] + red[6] + red[7];
  const float mu = s * (1.0f / CD);
  const float var = s2 * (1.0f / CD) - mu * mu;
  const float rs = rsqrtf(var + 1e-5f);
  const float4 gv = ((const float4*)g)[tid];
  const float4 bv = ((const float4*)be)[tid];
  ushort4 o;
  o.x = f2bf((v.x - mu) * rs * gv.x + bv.x);
  o.y = f2bf((v.y - mu) * rs * gv.y + bv.y);
  o.z = f2bf((v.z - mu) * rs * gv.z + bv.z);
  o.w = f2bf((v.w - mu) * rs * gv.w + bv.w);
  ((ushort4*)outp)[(size_t)row * (CD / 4) + tid] = o;
}

// ---------------- GEMM 256x256, 8-wave (2Mx4N), BK=64, 8-phase schedule with
// counted vmcnt (HK/m201 template in plain HIP). 512 threads, 128 KB LDS.
// Per tile T (4 phases q=0..3):
//   q: ds_read A-frag pair (2m x 2kk); q==0 also reads all B-frags (4n x 2kk)
//      stage 1 half-tile: q0->A0(T+1) q1->A1(T+1) q2->B0(T+2) q3->B1(T+2)
//      barrier; lgkmcnt(0); setprio(1); 16 MFMA; setprio(0);
//      closing barrier (at q3: vmcnt(4) first; vmcnt(0) entering last tile)
// Retirement makes this race-free: B-halves of T are only read in q0, so
// T+2's B can overwrite them from q2; A-halves are read through q3, so only
// T+1's A (other slot) is staged during T.
// EPI 0 (QKV): store bf16, Q pre-scaled 0.125, n0>=vsplit -> V^T.
// EPI 1: +bias, relu, store bf16.
template<int EPI>
__global__ __launch_bounds__(512)
void gemm_bt(const u16* __restrict__ A, const u16* __restrict__ Bt,
             void* __restrict__ Cout, const float* __restrict__ bias,
             int M, int N, int K,
             int ldc, int vsplit, u16* __restrict__ vtout)
{
  __shared__ __align__(16) u16 sA[2][2][128 * 64];   // [par][half] 64 KB
  __shared__ __align__(16) u16 sB[2][2][128 * 64];   // [par][half] 64 KB
  const int tid = threadIdx.x;
  const int wave = tid >> 6, lane = tid & 63;
  const int wm = wave >> 2, wn = wave & 3;           // 2 x 4 wave grid

  // XCD-banded tile decode (n-fastest)
  const int G = gridDim.x;
  const int flat = blockIdx.x;
  const int t0_ = (flat & 7) * (G >> 3) + (flat >> 3);
  const int NN = N >> 8;
  const int n_i = t0_ % NN;
  const int m_i = t0_ / NN;

  const int m0 = m_i * 256, n0 = n_i * 256;
  const int lq = lane >> 4, lr = lane & 15;
  const int l7 = lr & 7;
  const int sw0 = ((lq ^ l7) << 3);        // swizzled block offset, kk=0
  const int sw1 = (((4 + lq) ^ l7) << 3);  // kk=32

  f32x4 acc[8][4] = {};

  const u16* Ab = A + (size_t)m0 * K;
  const u16* Bb = Bt + (size_t)n0 * K;
  const int srow = lane >> 3;                    // 0..7 within a 1KB chunk
  const int scol = (((lane & 7) ^ srow)) * 8;    // swizzled staging column

  // stage one 128x64 half-tile (16 KB): 2 gloads per thread
  auto stageA = [&](int par, int h, int kt){
    const u16* src = Ab + (size_t)(h * 128) * K + kt * 64;
    u16* dst = &sA[par][h][0];
    #pragma unroll
    for (int i = 0; i < 2; i++){
      const int c = wave * 2 + i;                // chunk 0..15 (8 rows each)
      gload_lds16(src + (size_t)(c * 8 + srow) * K + scol, dst + c * 512);
    }
  };
  auto stageB = [&](int par, int h, int kt){
    const u16* src = Bb + (size_t)(h * 128) * K + kt * 64;
    u16* dst = &sB[par][h][0];
    #pragma unroll
    for (int i = 0; i < 2; i++){
      const int c = wave * 2 + i;
      gload_lds16(src + (size_t)(c * 8 + srow) * K + scol, dst + c * 512);
    }
  };

  const int nt = K >> 6;   // >= 16 here

  // prologue: T0 all 4 halves, then T1's B halves; vmcnt(4) = T0 landed
  stageB(0, 0, 0); stageB(0, 1, 0);
  stageA(0, 0, 0); stageA(0, 1, 0);
  stageB(1, 0, 1); stageB(1, 1, 1);
  asm volatile("s_waitcnt vmcnt(4)\n\ts_barrier" ::: "memory");

  short8 bF0[4], bF1[4];

  for (int t = 0; t < nt; t++){
    const int par = t & 1;
    const u16* aT = &sA[par][wm][0];
    const u16* bT = &sB[par][wn >> 1][0];
    const int bbase = (wn & 1) * 64;

    #pragma unroll
    for (int tq = 0; tq < 4; tq++){
      // ---- ds_reads for this phase (tile t)
      if (tq == 0){
        #pragma unroll
        for (int j = 0; j < 4; j++){
          bF0[j] = *(const short8*)&bT[(bbase + j * 16 + lr) * 64 + sw0];
          bF1[j] = *(const short8*)&bT[(bbase + j * 16 + lr) * 64 + sw1];
        }
      }
      const short8 a00 = *(const short8*)&aT[((tq * 2 + 0) * 16 + lr) * 64 + sw0];
      const short8 a01 = *(const short8*)&aT[((tq * 2 + 0) * 16 + lr) * 64 + sw1];
      const short8 a10 = *(const short8*)&aT[((tq * 2 + 1) * 16 + lr) * 64 + sw0];
      const short8 a11 = *(const short8*)&aT[((tq * 2 + 1) * 16 + lr) * 64 + sw1];

      // ---- stage schedule: q0/q1 -> (T+1) A halves, q2/q3 -> (T+2) B halves
      if (tq == 0){ if (t + 1 < nt) stageA(par ^ 1, 0, t + 1); }
      if (tq == 1){ if (t + 1 < nt) stageA(par ^ 1, 1, t + 1); }
      if (tq == 2){ if (t + 2 < nt) stageB(par, 0, t + 2); }
      if (tq == 3){ if (t + 2 < nt) stageB(par, 1, t + 2); }

      asm volatile("s_barrier" ::: "memory");
      asm volatile("s_waitcnt lgkmcnt(0)" ::: "memory");
      __builtin_amdgcn_sched_barrier(0);

      __builtin_amdgcn_s_setprio(1);
      #pragma unroll
      for (int j = 0; j < 4; j++){
        acc[tq * 2 + 0][j] = __builtin_amdgcn_mfma_f32_16x16x32_bf16(a00, bF0[j], acc[tq * 2 + 0][j], 0, 0, 0);
        acc[tq * 2 + 0][j] = __builtin_amdgcn_mfma_f32_16x16x32_bf16(a01, bF1[j], acc[tq * 2 + 0][j], 0, 0, 0);
        acc[tq * 2 + 1][j] = __builtin_amdgcn_mfma_f32_16x16x32_bf16(a10, bF0[j], acc[tq * 2 + 1][j], 0, 0, 0);
        acc[tq * 2 + 1][j] = __builtin_amdgcn_mfma_f32_16x16x32_bf16(a11, bF1[j], acc[tq * 2 + 1][j], 0, 0, 0);
      }
      __builtin_amdgcn_s_setprio(0);

      // ---- closing barrier; once per tile: counted vmcnt checkpoint
      if (tq == 3){
        if (t == nt - 2){
          asm volatile("s_waitcnt vmcnt(0)\n\ts_barrier" ::: "memory");
        } else if (t < nt - 2){
          asm volatile("s_waitcnt vmcnt(4)\n\ts_barrier" ::: "memory");
        } else {
          asm volatile("s_barrier" ::: "memory");
        }
      } else {
        asm volatile("s_barrier" ::: "memory");
      }
    }
  }

  if (EPI == 0 && n0 >= vsplit){
    // V block: store transposed into vt[(b*16+h)*64+d][s], s = 4 consecutive rows
    #pragma unroll
    for (int mf = 0; mf < 8; mf++){
      const int row0 = m0 + wm * 128 + mf * 16 + lq * 4;
      const int bb = row0 >> 11, s = row0 & 2047;
      #pragma unroll
      for (int nf = 0; nf < 4; nf++){
        const int col = n0 - vsplit + wn * 64 + nf * 16 + lr;  // 0..1023 = h*64+d
        ushort4 o;
        o.x = f2bf(acc[mf][nf][0]); o.y = f2bf(acc[mf][nf][1]);
        o.z = f2bf(acc[mf][nf][2]); o.w = f2bf(acc[mf][nf][3]);
        *(ushort4*)&vtout[((size_t)(bb * 1024 + col)) * CS + s] = o;
      }
    }
    return;
  }

  // Q pre-scale for attention (EPI 0 / QKV only): cols < 1024 are Q
  const float osc = (EPI == 0 && n0 < 1024) ? 0.125f : 1.0f;

  #pragma unroll
  for (int mf = 0; mf < 8; mf++){
    const int row = m0 + wm * 128 + mf * 16 + lq * 4;
    #pragma unroll
    for (int nf = 0; nf < 4; nf++){
      const int col = n0 + wn * 64 + nf * 16 + lr;
      #pragma unroll
      for (int r = 0; r < 4; r++){
        float v = acc[mf][nf][r];
        const size_t off = (size_t)(row + r) * ldc + col;
        if (EPI == 0){
          ((u16*)Cout)[off] = f2bf(v * osc);
        } else {
          v += bias[col]; v = v > 0.0f ? v : 0.0f;
          ((u16*)Cout)[off] = f2bf(v);
        }
      }
    }
  }
}

// ---------------- GEMM 64x128, dbuf + vmcnt pipeline + XOR-swizzled LDS:
// Cout[M,N] (f32) = resid[M,N] (f32) + A[M,K] (bf16) * Bt[N,K]^T
__global__ __launch_bounds__(256)
void gemm_bt64(const u16* __restrict__ A, const u16* __restrict__ Bt,
               const float* __restrict__ resid, float* __restrict__ Cout,
               int M, int N, int K)
{
  __shared__ __align__(16) u16 lA[2][64 * 64];    // 16 KB
  __shared__ __align__(16) u16 lB[2][128 * 64];   // 32 KB
  const int tid = threadIdx.x;
  const int wave = tid >> 6, lane = tid & 63;

  const int G = gridDim.x;
  const int flat = blockIdx.x;
  const int t = (flat & 7) * (G >> 3) + (flat >> 3);
  const int NN = N >> 7;
  const int n_i = t % NN;
  const int m_i = t / NN;
  const int m0 = m_i * 64, n0 = n_i * 128;
  const int lq = lane >> 4, lr = lane & 15;
  const int l7 = lr & 7;
  const int sw0 = ((lq ^ l7) << 3);
  const int sw1 = (((4 + lq) ^ l7) << 3);

  f32x4 acc[4][2] = {};

  const u16* Ab = A + (size_t)m0 * K;
  const u16* Bb = Bt + (size_t)n0 * K;
  const int srow = lane >> 3;
  const int scol = (((lane & 7) ^ srow)) * 8;

  auto stage = [&](int buf, int kt){
    const int k0 = kt * 64;
    #pragma unroll
    for (int i = 0; i < 6; i++){
      const int c = i * 4 + wave;          // 0..23: chunks 0-7 = A, 8-23 = B
      if (c < 8){
        gload_lds16(Ab + (size_t)(c * 8 + srow) * K + k0 + scol, &lA[buf][c * 512]);
      } else {
        const int cb2 = c - 8;
        gload_lds16(Bb + (size_t)(cb2 * 8 + srow) * K + k0 + scol, &lB[buf][cb2 * 512]);
      }
    }
  };

  const int nit = K >> 6;
  stage(0, 0);
  for (int i = 0; i < nit; i++){
    const int cb = i & 1;
    if (i + 1 < nit){
      stage(cb ^ 1, i + 1);
      asm volatile("s_waitcnt vmcnt(6)\n\ts_barrier" ::: "memory");
    } else {
      asm volatile("s_waitcnt vmcnt(0)\n\ts_barrier" ::: "memory");
    }
    #pragma unroll
    for (int kh = 0; kh < 2; kh++){
      const int sw = kh ? sw1 : sw0;
      short8 aF[4], bF[2];
      #pragma unroll
      for (int i2 = 0; i2 < 4; i2++) aF[i2] = *(const short8*)&lA[cb][(i2 * 16 + lr) * 64 + sw];
      #pragma unroll
      for (int j = 0; j < 2; j++) bF[j] = *(const short8*)&lB[cb][(wave * 32 + j * 16 + lr) * 64 + sw];
      #pragma unroll
      for (int i2 = 0; i2 < 4; i2++)
        #pragma unroll
        for (int j = 0; j < 2; j++)
          acc[i2][j] = __builtin_amdgcn_mfma_f32_16x16x32_bf16(aF[i2], bF[j], acc[i2][j], 0, 0, 0);
    }
    asm volatile("s_barrier" ::: "memory");
  }

  #pragma unroll
  for (int i = 0; i < 4; i++){
    const int row = m0 + i * 16 + lq * 4;
    #pragma unroll
    for (int j = 0; j < 2; j++){
      const int col = n0 + wave * 32 + j * 16 + lr;
      #pragma unroll
      for (int r = 0; r < 4; r++){
        const size_t off = (size_t)(row + r) * N + col;
        Cout[off] = resid[off] + acc[i][j][r];
      }
    }
  }
}

// ---------------- causal flash attention, dbuf + vmcnt pipeline + swizzled KV.
// Grid: x = bh (XCD L2 locality: same bh -> same XCD since (bh+32y)%8==bh%8),
//       y = q-block, LPT order (iq = 31-y so long blocks dispatch first).
// 1024 blocks -> 3 blocks/CU resident (LDS-capped) = 12 waves/CU.
// No running max; Q pre-scaled 0.125.
// qk: bf16 [B*S][2048] (Q | K), vt: bf16 [B*H*DH][S], out: bf16 [B*S][1024]
__global__ __launch_bounds__(256)
void attn_kernel(const u16* __restrict__ qk, const u16* __restrict__ vt,
                 u16* __restrict__ outp)
{
  __shared__ __align__(16) u16 lK[2][64 * 64];   // [key][d]  16 KB
  __shared__ __align__(16) u16 lVt[2][64 * 64];  // [d][key]  16 KB
  __shared__ __align__(16) u16 lP[4][16 * 72];   // per-wave P, padded  9 KB
  const int tid = threadIdx.x, wave = tid >> 6, lane = tid & 63;
  const int lq = lane >> 4, lr = lane & 15;
  const int l7 = lr & 7;
  const int sw0 = ((lq ^ l7) << 3);
  const int sw1 = (((4 + lq) ^ l7) << 3);
  const int bh = blockIdx.x, b = bh >> 4, h = bh & 15;
  const int RS = 2048;
  const int srow = lane >> 3;
  const int scol = (((lane & 7) ^ srow)) * 8;

  const size_t kbase = (size_t)(b * CS) * RS + 1024 + h * CDH;
  const size_t vbase = (size_t)(bh * CDH) * CS;
  u16* lPw = lP[wave];

  auto stageKV = [&](int buf, int kt){
    #pragma unroll
    for (int cc = 0; cc < 2; cc++){
      const int c = wave * 2 + cc;             // chunk 0..7, 8 rows each
      gload_lds16(qk + kbase + (size_t)(kt * 64 + c * 8 + srow) * RS + scol, &lK[buf][c * 512]);
      gload_lds16(vt + vbase + (size_t)(c * 8 + srow) * CS + kt * 64 + scol, &lVt[buf][c * 512]);
    }
  };

  const int iq = (NQB - 1) - blockIdx.y;   // LPT: longest q-blocks first
  const int q0 = iq * 64;
  const int ktmax = iq + 1;

  // Q fragments (A-layout): m = lr, k = lq*8 + j (+32); already * 0.125
  const int qrow = b * CS + q0 + wave * 16 + lr;
  const u16* qp = qk + (size_t)qrow * RS + h * CDH;
  const short8 qf0 = *(const short8*)(qp + lq * 8);
  const short8 qf1 = *(const short8*)(qp + 32 + lq * 8);

  f32x4 o[4] = {};
  float lsum[4] = {0.0f, 0.0f, 0.0f, 0.0f};

  stageKV(0, 0);
  for (int kt = 0; kt < ktmax; ++kt){
    const int cb = kt & 1;
    if (kt + 1 < ktmax){
      stageKV(cb ^ 1, kt + 1);
      asm volatile("s_waitcnt vmcnt(4)\n\ts_barrier" ::: "memory");
    } else {
      asm volatile("s_waitcnt vmcnt(0)\n\ts_barrier" ::: "memory");
    }

    // S = Q K^T : 16 q-rows x 64 keys (pre-scaled)
    f32x4 s[4] = {};
    #pragma unroll
    for (int nb = 0; nb < 4; nb++){
      const short8 bk0 = *(const short8*)&lK[cb][(nb * 16 + lr) * 64 + sw0];
      const short8 bk1 = *(const short8*)&lK[cb][(nb * 16 + lr) * 64 + sw1];
      s[nb] = __builtin_amdgcn_mfma_f32_16x16x32_bf16(qf0, bk0, s[nb], 0, 0, 0);
      s[nb] = __builtin_amdgcn_mfma_f32_16x16x32_bf16(qf1, bk1, s[nb], 0, 0, 0);
    }

    const bool diag = (kt + 1) == ktmax;       // only diagonal tile needs mask
    const int qg = q0 + wave * 16 + lq * 4;
    #pragma unroll
    for (int r = 0; r < 4; r++){
      float e0 = __expf(s[0][r]);
      float e1 = __expf(s[1][r]);
      float e2 = __expf(s[2][r]);
      float e3 = __expf(s[3][r]);
      if (diag){
        const int q = qg + r, kb = kt * 64 + lr;
        e0 = (kb      <= q) ? e0 : 0.0f;
        e1 = (kb + 16 <= q) ? e1 : 0.0f;
        e2 = (kb + 32 <= q) ? e2 : 0.0f;
        e3 = (kb + 48 <= q) ? e3 : 0.0f;
      }
      lsum[r] += (e0 + e1) + (e2 + e3);
      const int prow = (lq * 4 + r) * 72;
      lPw[prow + lr]      = f2bf_pos(e0);
      lPw[prow + 16 + lr] = f2bf_pos(e1);
      lPw[prow + 32 + lr] = f2bf_pos(e2);
      lPw[prow + 48 + lr] = f2bf_pos(e3);
    }

    // P: C-layout -> A-layout via per-wave LDS
    asm volatile("s_waitcnt lgkmcnt(0)" ::: "memory");
    const short8 pf0 = *(const short8*)&lPw[lr * 72 + lq * 8];
    const short8 pf1 = *(const short8*)&lPw[lr * 72 + 32 + lq * 8];

    #pragma unroll
    for (int nb = 0; nb < 4; nb++){
      const short8 bv0 = *(const short8*)&lVt[cb][(nb * 16 + lr) * 64 + sw0];
      const short8 bv1 = *(const short8*)&lVt[cb][(nb * 16 + lr) * 64 + sw1];
      o[nb] = __builtin_amdgcn_mfma_f32_16x16x32_bf16(pf0, bv0, o[nb], 0, 0, 0);
      o[nb] = __builtin_amdgcn_mfma_f32_16x16x32_bf16(pf1, bv1, o[nb], 0, 0, 0);
    }
    // protect buffer cb from overwrite by kt+2's stage
    asm volatile("s_barrier" ::: "memory");
  }

  // reduction: sum over the 16 key-lanes (lr)
  #pragma unroll
  for (int r = 0; r < 4; r++){
    float l = lsum[r];
    l += __shfl_xor(l, 1);
    l += __shfl_xor(l, 2);
    l += __shfl_xor(l, 4);
    l += __shfl_xor(l, 8);
    const float inv = __builtin_amdgcn_rcpf(l);
    const size_t row = (size_t)(b * CS + q0 + wave * 16 + lq * 4 + r);
    #pragma unroll
    for (int nb = 0; nb < 4; nb++)
      outp[row * CD + h * CDH + nb * 16 + lr] = f2bf(o[nb][r] * inv);
  }
}

extern "C" void kernel_launch(void* const* d_in, const int* in_sizes, int n_in,
                              void* d_out, int out_size, void* d_ws, size_t ws_size,
                              hipStream_t stream)
{
  const float* x   = (const float*)d_in[0];
  const float* Wq  = (const float*)d_in[2];
  const float* Wk  = (const float*)d_in[3];
  const float* Wv  = (const float*)d_in[4];
  const float* Wo  = (const float*)d_in[5];
  const float* w1  = (const float*)d_in[6];
  const float* b1  = (const float*)d_in[7];
  const float* w2  = (const float*)d_in[8];
  const float* b2  = (const float*)d_in[9];
  const float* g1  = (const float*)d_in[10];
  const float* be1 = (const float*)d_in[11];
  const float* g2  = (const float*)d_in[12];
  const float* be2 = (const float*)d_in[13];
  float* out = (float*)d_out;

  char* ws = (char*)d_ws;
  const size_t MB = 1u << 20;
  u16* yln    = (u16*)(ws);              // [4096][1024] bf16 (also hn)       8 MB
  u16* qk     = (u16*)(ws + 8  * MB);    // [4096][2048] bf16 (Q|K)          16 MB
  u16* vt     = (u16*)(ws + 24 * MB);    // [B*H*64][2048] bf16 (V^T)         8 MB
  u16* attn   = (u16*)(ws + 32 * MB);    // [4096][1024] bf16                 8 MB
  u16* mid    = (u16*)(ws + 40 * MB);    // [4096][4096] bf16                32 MB
  u16* Wqkv_t = (u16*)(ws + 72 * MB);    // [3072][1024] bf16                 6 MB
  u16* Wo_t   = (u16*)(ws + 78 * MB);    // [1024][1024] bf16                 2 MB
  u16* w1_t   = (u16*)(ws + 80 * MB);    // [4096][1024] bf16                 8 MB
  u16* w2_t   = (u16*)(ws + 88 * MB);    // [1024][4096] bf16                 8 MB

  const int M = CB * CS;  // 4096
  const int BIG = 1 << 30;

  // prep: all 6 transposes + LN1 fused in one launch
  TPAll pa;
  pa.s[0] = Wq; pa.s[1] = Wk; pa.s[2] = Wv; pa.s[3] = Wo; pa.s[4] = w1; pa.s[5] = w2;
  pa.d[0] = Wqkv_t;
  pa.d[1] = Wqkv_t + (size_t)CD * CD;
  pa.d[2] = Wqkv_t + (size_t)2 * CD * CD;
  pa.d[3] = Wo_t;
  pa.d[4] = w1_t;
  pa.d[5] = w2_t;
  prep_all<<<4 * 4096, 256, 0, stream>>>(pa, x, g1, be1, yln);

  // QKV: Q,K -> qk (ldc=2048, Q pre-scaled 0.125); V -> vt (transposed)
  // 256x256 tiles: grid = (4096/256) * (3072/256) = 16 * 12 = 192
  gemm_bt<0><<<192, 512, 0, stream>>>(yln, Wqkv_t, qk, nullptr, M, 3 * CD, CD, 2048, 2048, vt);
  // attention (grid: x=bh for XCD L2 locality, y=q-block LPT order)
  attn_kernel<<<dim3(CB * CH, NQB), 256, 0, stream>>>(qk, vt, attn);
  // h = x + attn @ Wo   (64x128 tiles, dbuf pipeline, resid = x)
  gemm_bt64<<<64 * 8, 256, 0, stream>>>(attn, Wo_t, x, out, M, CD, CD);
  // LN2: h -> hn (bf16); also out = h + b2 in-place (residual+bias for FFN2)
  ln_bf16<2><<<M, 256, 0, stream>>>(out, g2, be2, yln, (float4*)out, b2);
  // mid = relu(hn @ w1 + b1)  (256x256 8-phase pipeline, grid 16*16)
  gemm_bt<1><<<256, 512, 0, stream>>>(yln, w1_t, mid, b1, M, CDFF, CD, CDFF, BIG, nullptr);
  // out = (h + b2) + mid @ w2   (64x128 tiles, dbuf pipeline, 64 k-iters)
  gemm_bt64<<<64 * 8, 256, 0, stream>>>(mid, w2_t, out, out, M, CD, CDFF);
}

// Round 4
// 304.517 us; speedup vs baseline: 1.0309x; 1.0309x over previous
//
#include <hip/hip_runtime.h>

typedef unsigned short u16;
typedef __attribute__((ext_vector_type(8))) short short8;
typedef __attribute__((ext_vector_type(4))) float f32x4;

#define CB 2
#define CS 2048
#define CD 1024
#define CH 16
#define CDH 64
#define CDFF 4096
#define NQB (CS / 64)   // 32 q-blocks of 64

__device__ __forceinline__ u16 f2bf(float f){
  union { float f; unsigned u; } x; x.f = f;
  unsigned r = (x.u + 0x7fffu + ((x.u >> 16) & 1u)) >> 16;
  return (u16)r;
}

// cheap round for positive values (P matrix): round-half-up, 2 VALU ops
__device__ __forceinline__ u16 f2bf_pos(float f){
  union { float f; unsigned u; } x; x.f = f;
  return (u16)((x.u + 0x8000u) >> 16);
}

__device__ __forceinline__ void gload_lds16(const void* g, void* l){
  __builtin_amdgcn_global_load_lds(
    (const __attribute__((address_space(1))) void*)(unsigned long long)g,
    (__attribute__((address_space(3))) void*)(unsigned long long)l,
    16, 0, 0);
}

// LDS XOR swizzle: LDS 8-elem block j of row r holds global block j^(r&7).
// Staging loads global col block (lane&7)^srow; fragment reads XOR with lr&7.
// Kills the 16-way bank conflict of the row-stride-128B layout.

// ---------------- fused prep: all 6 weight transposes + LN1, one launch
struct TPAll { const float* s[6]; u16* d[6]; };

__global__ __launch_bounds__(256)
void prep_all(TPAll p, const float* __restrict__ x, const float* __restrict__ g1,
              const float* __restrict__ be1, u16* __restrict__ yln)
{
  const int g = blockIdx.x >> 12;
  const int id = blockIdx.x & 4095;
  const int tid = threadIdx.x;

  if (g == 3){
    // ---- LN1 row
    const int row = id;
    const int lane = tid & 63, wave = tid >> 6;
    const float4 v = ((const float4*)(x + (size_t)row * CD))[tid];
    float s  = v.x + v.y + v.z + v.w;
    float s2 = v.x*v.x + v.y*v.y + v.z*v.z + v.w*v.w;
    #pragma unroll
    for (int m = 1; m < 64; m <<= 1){ s += __shfl_xor(s, m); s2 += __shfl_xor(s2, m); }
    __shared__ float red[8];
    if (lane == 0){ red[wave] = s; red[4 + wave] = s2; }
    __syncthreads();
    s  = red[0] + red[1] + red[2] + red[3];
    s2 = red[4] + red[5] + red[6] + red[7];
    const float mu = s * (1.0f / CD);
    const float var = s2 * (1.0f / CD) - mu * mu;
    const float rs = rsqrtf(var + 1e-5f);
    const float4 gv = ((const float4*)g1)[tid];
    const float4 bv = ((const float4*)be1)[tid];
    ushort4 o;
    o.x = f2bf((v.x - mu) * rs * gv.x + bv.x);
    o.y = f2bf((v.y - mu) * rs * gv.y + bv.y);
    o.z = f2bf((v.z - mu) * rs * gv.z + bv.z);
    o.w = f2bf((v.w - mu) * rs * gv.w + bv.w);
    ((ushort4*)yln)[(size_t)row * (CD / 4) + tid] = o;
    return;
  }

  // ---- transpose tile
  __shared__ float t[32][33];
  const float* __restrict__ in;
  u16* __restrict__ out;
  int K, N, n0, k0;
  if (g == 0){
    const int w = id >> 10, tile = id & 1023;
    in = p.s[w]; out = p.d[w]; K = 1024; N = 1024;
    n0 = (tile & 31) * 32; k0 = (tile >> 5) * 32;
  } else if (g == 1){
    in = p.s[4]; out = p.d[4]; K = 1024; N = 4096;
    n0 = (id & 127) * 32; k0 = (id >> 7) * 32;
  } else {
    in = p.s[5]; out = p.d[5]; K = 4096; N = 1024;
    n0 = (id & 31) * 32; k0 = (id >> 5) * 32;
  }
  const int c = tid & 31, r4 = tid >> 5;
  #pragma unroll
  for (int i = 0; i < 4; i++){
    int r = r4 + i * 8;
    t[r][c] = in[(size_t)(k0 + r) * N + n0 + c];
  }
  __syncthreads();
  #pragma unroll
  for (int i = 0; i < 4; i++){
    int r = r4 + i * 8;
    out[(size_t)(n0 + r) * K + k0 + c] = f2bf(t[c][r]);
  }
}

// ---------------- LayerNorm: fp32 row [1024] -> bf16 row, one block per row
// MODE 0: LN only.  MODE 2: also write aux = v + bias (fp32, may alias xin)
template<int MODE>
__global__ __launch_bounds__(256)
void ln_bf16(const float* __restrict__ xin, const float* __restrict__ g,
             const float* __restrict__ be, u16* __restrict__ outp,
             float4* __restrict__ aux, const float* __restrict__ bias)
{
  const int row = blockIdx.x, tid = threadIdx.x;
  const int lane = tid & 63, wave = tid >> 6;
  const float4 v = ((const float4*)(xin + (size_t)row * CD))[tid];
  float s  = v.x + v.y + v.z + v.w;
  float s2 = v.x*v.x + v.y*v.y + v.z*v.z + v.w*v.w;
  #pragma unroll
  for (int m = 1; m < 64; m <<= 1){ s += __shfl_xor(s, m); s2 += __shfl_xor(s2, m); }
  __shared__ float red[8];
  if (lane == 0){ red[wave] = s; red[4 + wave] = s2; }

  if (MODE == 2){
    const float4 b4 = ((const float4*)bias)[tid];
    float4 w = v;
    w.x += b4.x; w.y += b4.y; w.z += b4.z; w.w += b4.w;
    aux[(size_t)row * 256 + tid] = w;
  }

  __syncthreads();
  s  = red[0] + red[1] + red[2] + red[3];
  s2 = red[4] + red[5] + red[6] + red[7];
  const float mu = s * (1.0f / CD);
  const float var = s2 * (1.0f / CD) - mu * mu;
  const float rs = rsqrtf(var + 1e-5f);
  const float4 gv = ((const float4*)g)[tid];
  const float4 bv = ((const float4*)be)[tid];
  ushort4 o;
  o.x = f2bf((v.x - mu) * rs * gv.x + bv.x);
  o.y = f2bf((v.y - mu) * rs * gv.y + bv.y);
  o.z = f2bf((v.z - mu) * rs * gv.z + bv.z);
  o.w = f2bf((v.w - mu) * rs * gv.w + bv.w);
  ((ushort4*)outp)[(size_t)row * (CD / 4) + tid] = o;
}

// ---------------- GEMM 256x256, 8-wave (2Mx4N), BK=64, 8-phase schedule with
// counted vmcnt (HK/m201 template in plain HIP). 512 threads, 128 KB LDS.
// Per tile T (4 phases q=0..3):
//   q: ds_read A-frag pair (2m x 2kk); q==0 also reads all B-frags (4n x 2kk)
//      stage 1 half-tile: q0->A0(T+1) q1->A1(T+1) q2->B0(T+2) q3->B1(T+2)
//      barrier; lgkmcnt(0); setprio(1); 16 MFMA; setprio(0);
//      closing barrier (at q3: vmcnt(4) first; vmcnt(0) entering last tile)
// Retirement makes this race-free: B-halves of T are only read in q0, so
// T+2's B can overwrite them from q2; A-halves are read through q3, so only
// T+1's A (other slot) is staged during T.
// EPI 0 (QKV): store bf16, Q pre-scaled 0.125, n0>=vsplit -> V^T.
// EPI 1: +bias, relu, store bf16.
template<int EPI>
__global__ __launch_bounds__(512)
void gemm_bt(const u16* __restrict__ A, const u16* __restrict__ Bt,
             void* __restrict__ Cout, const float* __restrict__ bias,
             int M, int N, int K,
             int ldc, int vsplit, u16* __restrict__ vtout)
{
  __shared__ __align__(16) u16 sA[2][2][128 * 64];   // [par][half] 64 KB
  __shared__ __align__(16) u16 sB[2][2][128 * 64];   // [par][half] 64 KB
  const int tid = threadIdx.x;
  const int wave = tid >> 6, lane = tid & 63;
  const int wm = wave >> 2, wn = wave & 3;           // 2 x 4 wave grid

  // XCD-banded tile decode (n-fastest)
  const int G = gridDim.x;
  const int flat = blockIdx.x;
  const int t0_ = (flat & 7) * (G >> 3) + (flat >> 3);
  const int NN = N >> 8;
  const int n_i = t0_ % NN;
  const int m_i = t0_ / NN;

  const int m0 = m_i * 256, n0 = n_i * 256;
  const int lq = lane >> 4, lr = lane & 15;
  const int l7 = lr & 7;
  const int sw0 = ((lq ^ l7) << 3);        // swizzled block offset, kk=0
  const int sw1 = (((4 + lq) ^ l7) << 3);  // kk=32

  f32x4 acc[8][4] = {};

  const u16* Ab = A + (size_t)m0 * K;
  const u16* Bb = Bt + (size_t)n0 * K;
  const int srow = lane >> 3;                    // 0..7 within a 1KB chunk
  const int scol = (((lane & 7) ^ srow)) * 8;    // swizzled staging column

  // stage one 128x64 half-tile (16 KB): 2 gloads per thread
  auto stageA = [&](int par, int h, int kt){
    const u16* src = Ab + (size_t)(h * 128) * K + kt * 64;
    u16* dst = &sA[par][h][0];
    #pragma unroll
    for (int i = 0; i < 2; i++){
      const int c = wave * 2 + i;                // chunk 0..15 (8 rows each)
      gload_lds16(src + (size_t)(c * 8 + srow) * K + scol, dst + c * 512);
    }
  };
  auto stageB = [&](int par, int h, int kt){
    const u16* src = Bb + (size_t)(h * 128) * K + kt * 64;
    u16* dst = &sB[par][h][0];
    #pragma unroll
    for (int i = 0; i < 2; i++){
      const int c = wave * 2 + i;
      gload_lds16(src + (size_t)(c * 8 + srow) * K + scol, dst + c * 512);
    }
  };

  const int nt = K >> 6;   // >= 16 here

  // prologue: T0 all 4 halves, then T1's B halves; vmcnt(4) = T0 landed
  stageB(0, 0, 0); stageB(0, 1, 0);
  stageA(0, 0, 0); stageA(0, 1, 0);
  stageB(1, 0, 1); stageB(1, 1, 1);
  asm volatile("s_waitcnt vmcnt(4)\n\ts_barrier" ::: "memory");

  short8 bF0[4], bF1[4];

  for (int t = 0; t < nt; t++){
    const int par = t & 1;
    const u16* aT = &sA[par][wm][0];
    const u16* bT = &sB[par][wn >> 1][0];
    const int bbase = (wn & 1) * 64;

    #pragma unroll
    for (int tq = 0; tq < 4; tq++){
      // ---- ds_reads for this phase (tile t)
      if (tq == 0){
        #pragma unroll
        for (int j = 0; j < 4; j++){
          bF0[j] = *(const short8*)&bT[(bbase + j * 16 + lr) * 64 + sw0];
          bF1[j] = *(const short8*)&bT[(bbase + j * 16 + lr) * 64 + sw1];
        }
      }
      const short8 a00 = *(const short8*)&aT[((tq * 2 + 0) * 16 + lr) * 64 + sw0];
      const short8 a01 = *(const short8*)&aT[((tq * 2 + 0) * 16 + lr) * 64 + sw1];
      const short8 a10 = *(const short8*)&aT[((tq * 2 + 1) * 16 + lr) * 64 + sw0];
      const short8 a11 = *(const short8*)&aT[((tq * 2 + 1) * 16 + lr) * 64 + sw1];

      // ---- stage schedule: q0/q1 -> (T+1) A halves, q2/q3 -> (T+2) B halves
      if (tq == 0){ if (t + 1 < nt) stageA(par ^ 1, 0, t + 1); }
      if (tq == 1){ if (t + 1 < nt) stageA(par ^ 1, 1, t + 1); }
      if (tq == 2){ if (t + 2 < nt) stageB(par, 0, t + 2); }
      if (tq == 3){ if (t + 2 < nt) stageB(par, 1, t + 2); }

      asm volatile("s_barrier" ::: "memory");
      asm volatile("s_waitcnt lgkmcnt(0)" ::: "memory");
      __builtin_amdgcn_sched_barrier(0);

      __builtin_amdgcn_s_setprio(1);
      #pragma unroll
      for (int j = 0; j < 4; j++){
        acc[tq * 2 + 0][j] = __builtin_amdgcn_mfma_f32_16x16x32_bf16(a00, bF0[j], acc[tq * 2 + 0][j], 0, 0, 0);
        acc[tq * 2 + 0][j] = __builtin_amdgcn_mfma_f32_16x16x32_bf16(a01, bF1[j], acc[tq * 2 + 0][j], 0, 0, 0);
        acc[tq * 2 + 1][j] = __builtin_amdgcn_mfma_f32_16x16x32_bf16(a10, bF0[j], acc[tq * 2 + 1][j], 0, 0, 0);
        acc[tq * 2 + 1][j] = __builtin_amdgcn_mfma_f32_16x16x32_bf16(a11, bF1[j], acc[tq * 2 + 1][j], 0, 0, 0);
      }
      __builtin_amdgcn_s_setprio(0);

      // ---- closing barrier; once per tile: counted vmcnt checkpoint
      if (tq == 3){
        if (t == nt - 2){
          asm volatile("s_waitcnt vmcnt(0)\n\ts_barrier" ::: "memory");
        } else if (t < nt - 2){
          asm volatile("s_waitcnt vmcnt(4)\n\ts_barrier" ::: "memory");
        } else {
          asm volatile("s_barrier" ::: "memory");
        }
      } else {
        asm volatile("s_barrier" ::: "memory");
      }
    }
  }

  if (EPI == 0 && n0 >= vsplit){
    // V block: store transposed into vt[(b*16+h)*64+d][s], s = 4 consecutive rows
    #pragma unroll
    for (int mf = 0; mf < 8; mf++){
      const int row0 = m0 + wm * 128 + mf * 16 + lq * 4;
      const int bb = row0 >> 11, s = row0 & 2047;
      #pragma unroll
      for (int nf = 0; nf < 4; nf++){
        const int col = n0 - vsplit + wn * 64 + nf * 16 + lr;  // 0..1023 = h*64+d
        ushort4 o;
        o.x = f2bf(acc[mf][nf][0]); o.y = f2bf(acc[mf][nf][1]);
        o.z = f2bf(acc[mf][nf][2]); o.w = f2bf(acc[mf][nf][3]);
        *(ushort4*)&vtout[((size_t)(bb * 1024 + col)) * CS + s] = o;
      }
    }
    return;
  }

  // Q pre-scale for attention (EPI 0 / QKV only): cols < 1024 are Q
  const float osc = (EPI == 0 && n0 < 1024) ? 0.125f : 1.0f;

  #pragma unroll
  for (int mf = 0; mf < 8; mf++){
    const int row = m0 + wm * 128 + mf * 16 + lq * 4;
    #pragma unroll
    for (int nf = 0; nf < 4; nf++){
      const int col = n0 + wn * 64 + nf * 16 + lr;
      #pragma unroll
      for (int r = 0; r < 4; r++){
        float v = acc[mf][nf][r];
        const size_t off = (size_t)(row + r) * ldc + col;
        if (EPI == 0){
          ((u16*)Cout)[off] = f2bf(v * osc);
        } else {
          v += bias[col]; v = v > 0.0f ? v : 0.0f;
          ((u16*)Cout)[off] = f2bf(v);
        }
      }
    }
  }
}

// ---------------- GEMM 64x128, dbuf + vmcnt pipeline + XOR-swizzled LDS:
// Cout[M,N] (f32) = resid[M,N] (f32) + A[M,K] (bf16) * Bt[N,K]^T
__global__ __launch_bounds__(256)
void gemm_bt64(const u16* __restrict__ A, const u16* __restrict__ Bt,
               const float* __restrict__ resid, float* __restrict__ Cout,
               int M, int N, int K)
{
  __shared__ __align__(16) u16 lA[2][64 * 64];    // 16 KB
  __shared__ __align__(16) u16 lB[2][128 * 64];   // 32 KB
  const int tid = threadIdx.x;
  const int wave = tid >> 6, lane = tid & 63;

  const int G = gridDim.x;
  const int flat = blockIdx.x;
  const int t = (flat & 7) * (G >> 3) + (flat >> 3);
  const int NN = N >> 7;
  const int n_i = t % NN;
  const int m_i = t / NN;
  const int m0 = m_i * 64, n0 = n_i * 128;
  const int lq = lane >> 4, lr = lane & 15;
  const int l7 = lr & 7;
  const int sw0 = ((lq ^ l7) << 3);
  const int sw1 = (((4 + lq) ^ l7) << 3);

  f32x4 acc[4][2] = {};

  const u16* Ab = A + (size_t)m0 * K;
  const u16* Bb = Bt + (size_t)n0 * K;
  const int srow = lane >> 3;
  const int scol = (((lane & 7) ^ srow)) * 8;

  auto stage = [&](int buf, int kt){
    const int k0 = kt * 64;
    #pragma unroll
    for (int i = 0; i < 6; i++){
      const int c = i * 4 + wave;          // 0..23: chunks 0-7 = A, 8-23 = B
      if (c < 8){
        gload_lds16(Ab + (size_t)(c * 8 + srow) * K + k0 + scol, &lA[buf][c * 512]);
      } else {
        const int cb2 = c - 8;
        gload_lds16(Bb + (size_t)(cb2 * 8 + srow) * K + k0 + scol, &lB[buf][cb2 * 512]);
      }
    }
  };

  const int nit = K >> 6;
  stage(0, 0);
  for (int i = 0; i < nit; i++){
    const int cb = i & 1;
    if (i + 1 < nit){
      stage(cb ^ 1, i + 1);
      asm volatile("s_waitcnt vmcnt(6)\n\ts_barrier" ::: "memory");
    } else {
      asm volatile("s_waitcnt vmcnt(0)\n\ts_barrier" ::: "memory");
    }
    #pragma unroll
    for (int kh = 0; kh < 2; kh++){
      const int sw = kh ? sw1 : sw0;
      short8 aF[4], bF[2];
      #pragma unroll
      for (int i2 = 0; i2 < 4; i2++) aF[i2] = *(const short8*)&lA[cb][(i2 * 16 + lr) * 64 + sw];
      #pragma unroll
      for (int j = 0; j < 2; j++) bF[j] = *(const short8*)&lB[cb][(wave * 32 + j * 16 + lr) * 64 + sw];
      #pragma unroll
      for (int i2 = 0; i2 < 4; i2++)
        #pragma unroll
        for (int j = 0; j < 2; j++)
          acc[i2][j] = __builtin_amdgcn_mfma_f32_16x16x32_bf16(aF[i2], bF[j], acc[i2][j], 0, 0, 0);
    }
    asm volatile("s_barrier" ::: "memory");
  }

  #pragma unroll
  for (int i = 0; i < 4; i++){
    const int row = m0 + i * 16 + lq * 4;
    #pragma unroll
    for (int j = 0; j < 2; j++){
      const int col = n0 + wave * 32 + j * 16 + lr;
      #pragma unroll
      for (int r = 0; r < 4; r++){
        const size_t off = (size_t)(row + r) * N + col;
        Cout[off] = resid[off] + acc[i][j][r];
      }
    }
  }
}

// ---------------- causal flash attention, dbuf + vmcnt pipeline + swizzled KV.
// S^T trick: compute S^T = mfma(K, Q) (A/B frags have identical lane layouts,
// so this is an argument swap). Lane then holds keys nb*16+lq*4+r for qrow=lr,
// i.e. 4 CONSECUTIVE keys per register quad -> P writes pack into 4
// ds_write_b64 per KV-tile instead of 64 scalar ds_write_b16. PV path and P
// LDS layout ([qrow][72-pitch key]) unchanged. Row-sum becomes a per-lane
// scalar (reduce over lq via shfl_xor 16/32 at the end); epilogue fetches
// inv per qrow with one dynamic shfl per r.
// Grid: x = bh (XCD L2 locality), y = q-block, LPT order.
// qk: bf16 [B*S][2048] (Q | K), vt: bf16 [B*H*DH][S], out: bf16 [B*S][1024]
__global__ __launch_bounds__(256)
void attn_kernel(const u16* __restrict__ qk, const u16* __restrict__ vt,
                 u16* __restrict__ outp)
{
  __shared__ __align__(16) u16 lK[2][64 * 64];   // [key][d]  16 KB
  __shared__ __align__(16) u16 lVt[2][64 * 64];  // [d][key]  16 KB
  __shared__ __align__(16) u16 lP[4][16 * 72];   // per-wave P, padded  9 KB
  const int tid = threadIdx.x, wave = tid >> 6, lane = tid & 63;
  const int lq = lane >> 4, lr = lane & 15;
  const int l7 = lr & 7;
  const int sw0 = ((lq ^ l7) << 3);
  const int sw1 = (((4 + lq) ^ l7) << 3);
  const int bh = blockIdx.x, b = bh >> 4, h = bh & 15;
  const int RS = 2048;
  const int srow = lane >> 3;
  const int scol = (((lane & 7) ^ srow)) * 8;

  const size_t kbase = (size_t)(b * CS) * RS + 1024 + h * CDH;
  const size_t vbase = (size_t)(bh * CDH) * CS;
  u16* lPw = lP[wave];

  auto stageKV = [&](int buf, int kt){
    #pragma unroll
    for (int cc = 0; cc < 2; cc++){
      const int c = wave * 2 + cc;             // chunk 0..7, 8 rows each
      gload_lds16(qk + kbase + (size_t)(kt * 64 + c * 8 + srow) * RS + scol, &lK[buf][c * 512]);
      gload_lds16(vt + vbase + (size_t)(c * 8 + srow) * CS + kt * 64 + scol, &lVt[buf][c * 512]);
    }
  };

  const int iq = (NQB - 1) - blockIdx.y;   // LPT: longest q-blocks first
  const int q0 = iq * 64;
  const int ktmax = iq + 1;

  // Q fragments: per-lane row = lr, k = lq*8 + j (+32); already * 0.125.
  // Used as the B-operand of the S^T MFMA (same lane layout as A).
  const int qrow = b * CS + q0 + wave * 16 + lr;
  const u16* qp = qk + (size_t)qrow * RS + h * CDH;
  const short8 qf0 = *(const short8*)(qp + lq * 8);
  const short8 qf1 = *(const short8*)(qp + 32 + lq * 8);

  f32x4 o[4] = {};
  float lsum = 0.0f;
  const int qg = q0 + wave * 16 + lr;     // this lane's q index (S^T column)

  stageKV(0, 0);
  for (int kt = 0; kt < ktmax; ++kt){
    const int cb = kt & 1;
    if (kt + 1 < ktmax){
      stageKV(cb ^ 1, kt + 1);
      asm volatile("s_waitcnt vmcnt(4)\n\ts_barrier" ::: "memory");
    } else {
      asm volatile("s_waitcnt vmcnt(0)\n\ts_barrier" ::: "memory");
    }

    // S^T = K Q^T : 64 keys x 16 q-rows (pre-scaled). A = K-frag, B = Q-frag.
    f32x4 s[4] = {};
    #pragma unroll
    for (int nb = 0; nb < 4; nb++){
      const short8 bk0 = *(const short8*)&lK[cb][(nb * 16 + lr) * 64 + sw0];
      const short8 bk1 = *(const short8*)&lK[cb][(nb * 16 + lr) * 64 + sw1];
      s[nb] = __builtin_amdgcn_mfma_f32_16x16x32_bf16(bk0, qf0, s[nb], 0, 0, 0);
      s[nb] = __builtin_amdgcn_mfma_f32_16x16x32_bf16(bk1, qf1, s[nb], 0, 0, 0);
    }

    const bool diag = (kt + 1) == ktmax;       // only diagonal tile needs mask
    #pragma unroll
    for (int nb = 0; nb < 4; nb++){
      float e0 = __expf(s[nb][0]);
      float e1 = __expf(s[nb][1]);
      float e2 = __expf(s[nb][2]);
      float e3 = __expf(s[nb][3]);
      if (diag){
        const int kb = kt * 64 + nb * 16 + lq * 4;   // key of reg 0
        e0 = (kb     <= qg) ? e0 : 0.0f;
        e1 = (kb + 1 <= qg) ? e1 : 0.0f;
        e2 = (kb + 2 <= qg) ? e2 : 0.0f;
        e3 = (kb + 3 <= qg) ? e3 : 0.0f;
      }
      lsum += (e0 + e1) + (e2 + e3);
      ushort4 pw;
      pw.x = f2bf_pos(e0);
      pw.y = f2bf_pos(e1);
      pw.z = f2bf_pos(e2);
      pw.w = f2bf_pos(e3);
      // P[qrow=lr][key = nb*16 + lq*4 + 0..3] -- 4 consecutive keys, one b64
      *(ushort4*)&lPw[lr * 72 + nb * 16 + lq * 4] = pw;
    }

    // P: A-layout read (m=qrow=lr, k=lq*8+j) -- unchanged
    asm volatile("s_waitcnt lgkmcnt(0)" ::: "memory");
    const short8 pf0 = *(const short8*)&lPw[lr * 72 + lq * 8];
    const short8 pf1 = *(const short8*)&lPw[lr * 72 + 32 + lq * 8];

    #pragma unroll
    for (int nb = 0; nb < 4; nb++){
      const short8 bv0 = *(const short8*)&lVt[cb][(nb * 16 + lr) * 64 + sw0];
      const short8 bv1 = *(const short8*)&lVt[cb][(nb * 16 + lr) * 64 + sw1];
      o[nb] = __builtin_amdgcn_mfma_f32_16x16x32_bf16(pf0, bv0, o[nb], 0, 0, 0);
      o[nb] = __builtin_amdgcn_mfma_f32_16x16x32_bf16(pf1, bv1, o[nb], 0, 0, 0);
    }
    // protect buffer cb from overwrite by kt+2's stage
    asm volatile("s_barrier" ::: "memory");
  }

  // lsum holds this lane's partial over keys {nb*16+lq*4+0..3}; lanes with
  // the same lr (4 lq-groups) cover all 64 keys -> reduce over lane bits 4,5.
  float l = lsum;
  l += __shfl_xor(l, 16);
  l += __shfl_xor(l, 32);
  const float inv = __builtin_amdgcn_rcpf(l);   // valid for qrow = lr

  #pragma unroll
  for (int r = 0; r < 4; r++){
    // o[nb][r] is qrow = lq*4+r, d = nb*16+lr; fetch inv from lane lr'=lq*4+r
    const float invr = __shfl(inv, lq * 4 + r);
    const size_t row = (size_t)(b * CS + q0 + wave * 16 + lq * 4 + r);
    #pragma unroll
    for (int nb = 0; nb < 4; nb++)
      outp[row * CD + h * CDH + nb * 16 + lr] = f2bf(o[nb][r] * invr);
  }
}

extern "C" void kernel_launch(void* const* d_in, const int* in_sizes, int n_in,
                              void* d_out, int out_size, void* d_ws, size_t ws_size,
                              hipStream_t stream)
{
  const float* x   = (const float*)d_in[0];
  const float* Wq  = (const float*)d_in[2];
  const float* Wk  = (const float*)d_in[3];
  const float* Wv  = (const float*)d_in[4];
  const float* Wo  = (const float*)d_in[5];
  const float* w1  = (const float*)d_in[6];
  const float* b1  = (const float*)d_in[7];
  const float* w2  = (const float*)d_in[8];
  const float* b2  = (const float*)d_in[9];
  const float* g1  = (const float*)d_in[10];
  const float* be1 = (const float*)d_in[11];
  const float* g2  = (const float*)d_in[12];
  const float* be2 = (const float*)d_in[13];
  float* out = (float*)d_out;

  char* ws = (char*)d_ws;
  const size_t MB = 1u << 20;
  u16* yln    = (u16*)(ws);              // [4096][1024] bf16 (also hn)       8 MB
  u16* qk     = (u16*)(ws + 8  * MB);    // [4096][2048] bf16 (Q|K)          16 MB
  u16* vt     = (u16*)(ws + 24 * MB);    // [B*H*64][2048] bf16 (V^T)         8 MB
  u16* attn   = (u16*)(ws + 32 * MB);    // [4096][1024] bf16                 8 MB
  u16* mid    = (u16*)(ws + 40 * MB);    // [4096][4096] bf16                32 MB
  u16* Wqkv_t = (u16*)(ws + 72 * MB);    // [3072][1024] bf16                 6 MB
  u16* Wo_t   = (u16*)(ws + 78 * MB);    // [1024][1024] bf16                 2 MB
  u16* w1_t   = (u16*)(ws + 80 * MB);    // [4096][1024] bf16                 8 MB
  u16* w2_t   = (u16*)(ws + 88 * MB);    // [1024][4096] bf16                 8 MB

  const int M = CB * CS;  // 4096
  const int BIG = 1 << 30;

  // prep: all 6 transposes + LN1 fused in one launch
  TPAll pa;
  pa.s[0] = Wq; pa.s[1] = Wk; pa.s[2] = Wv; pa.s[3] = Wo; pa.s[4] = w1; pa.s[5] = w2;
  pa.d[0] = Wqkv_t;
  pa.d[1] = Wqkv_t + (size_t)CD * CD;
  pa.d[2] = Wqkv_t + (size_t)2 * CD * CD;
  pa.d[3] = Wo_t;
  pa.d[4] = w1_t;
  pa.d[5] = w2_t;
  prep_all<<<4 * 4096, 256, 0, stream>>>(pa, x, g1, be1, yln);

  // QKV: Q,K -> qk (ldc=2048, Q pre-scaled 0.125); V -> vt (transposed)
  // 256x256 tiles: grid = (4096/256) * (3072/256) = 16 * 12 = 192
  gemm_bt<0><<<192, 512, 0, stream>>>(yln, Wqkv_t, qk, nullptr, M, 3 * CD, CD, 2048, 2048, vt);
  // attention (grid: x=bh for XCD L2 locality, y=q-block LPT order)
  attn_kernel<<<dim3(CB * CH, NQB), 256, 0, stream>>>(qk, vt, attn);
  // h = x + attn @ Wo   (64x128 tiles, dbuf pipeline, resid = x)
  gemm_bt64<<<64 * 8, 256, 0, stream>>>(attn, Wo_t, x, out, M, CD, CD);
  // LN2: h -> hn (bf16); also out = h + b2 in-place (residual+bias for FFN2)
  ln_bf16<2><<<M, 256, 0, stream>>>(out, g2, be2, yln, (float4*)out, b2);
  // mid = relu(hn @ w1 + b1)  (256x256 8-phase pipeline, grid 16*16)
  gemm_bt<1><<<256, 512, 0, stream>>>(yln, w1_t, mid, b1, M, CDFF, CD, CDFF, BIG, nullptr);
  // out = (h + b2) + mid @ w2   (64x128 tiles, dbuf pipeline, 64 k-iters)
  gemm_bt64<<<64 * 8, 256, 0, stream>>>(mid, w2_t, out, out, M, CD, CDFF);
}